// Round 1
// baseline (1910.231 us; speedup 1.0000x reference)
//
#include <hip/hip_runtime.h>
#include <hip/hip_bf16.h>

// Problem constants (match reference)
#define NN 100000
#define NE 3200000
#define F_IN 512
#define NHID 64
#define NCLS 40

// ---------------------------------------------------------------------------
// GEMM1: H[N,64] = relu(F[N,512] @ W1[512,64] + b1)
// 64x64 tile per block, K-chunks of 16, fp32 (no fp32 MFMA on CDNA4).
// ---------------------------------------------------------------------------
__global__ __launch_bounds__(256) void gemm1_kernel(
    const float* __restrict__ F, const float* __restrict__ W1,
    const float* __restrict__ b1, float* __restrict__ H) {
  __shared__ float As[16][68];  // k-major: As[kk][row]; pad 68 keeps 16B align, ~2-way banks
  __shared__ float Bs[16][64];  // Bs[kk][col]
  const int tid = threadIdx.x;
  const int m0 = blockIdx.x * 64;
  const int ty = tid >> 4;          // 0..15 -> output rows ty*4..+3
  const int tx = tid & 15;          // output cols tx*4..+3
  const int lrowA = tid >> 2;       // 0..63
  const int lkA = (tid & 3) * 4;    // 0,4,8,12
  const int lkB = tid >> 4;         // 0..15
  const int lcolB = (tid & 15) * 4; // 0..60
  const bool rowok = (m0 + lrowA) < NN;
  const int rclamp = rowok ? (m0 + lrowA) : (NN - 1);
  const float* Fb = F + (long)rclamp * F_IN + lkA;

  float acc[4][4] = {};
  for (int k0 = 0; k0 < F_IN; k0 += 16) {
    float4 fa = *(const float4*)(Fb + k0);
    if (!rowok) fa = make_float4(0.f, 0.f, 0.f, 0.f);
    float4 wb = *(const float4*)(W1 + (long)(k0 + lkB) * NHID + lcolB);
    __syncthreads();  // previous-iter readers done
    As[lkA + 0][lrowA] = fa.x;
    As[lkA + 1][lrowA] = fa.y;
    As[lkA + 2][lrowA] = fa.z;
    As[lkA + 3][lrowA] = fa.w;
    *(float4*)&Bs[lkB][lcolB] = wb;
    __syncthreads();
#pragma unroll
    for (int kk = 0; kk < 16; ++kk) {
      float4 a = *(const float4*)&As[kk][ty * 4];
      float4 b = *(const float4*)&Bs[kk][tx * 4];
      float av[4] = {a.x, a.y, a.z, a.w};
      float bv[4] = {b.x, b.y, b.z, b.w};
#pragma unroll
      for (int i = 0; i < 4; ++i)
#pragma unroll
        for (int j = 0; j < 4; ++j) acc[i][j] = fmaf(av[i], bv[j], acc[i][j]);
    }
  }
  float4 bb = *(const float4*)(b1 + tx * 4);
  float bv[4] = {bb.x, bb.y, bb.z, bb.w};
#pragma unroll
  for (int i = 0; i < 4; ++i) {
    int r = m0 + ty * 4 + i;
    if (r < NN) {
      float4 o;
      o.x = fmaxf(acc[i][0] + bv[0], 0.f);
      o.y = fmaxf(acc[i][1] + bv[1], 0.f);
      o.z = fmaxf(acc[i][2] + bv[2], 0.f);
      o.w = fmaxf(acc[i][3] + bv[3], 0.f);
      *(float4*)(H + (long)r * NHID + tx * 4) = o;
    }
  }
}

// ---------------------------------------------------------------------------
// GEMM2: X0[N,40] = H[N,64] @ W2[64,40] + b2   (thread per node)
// ---------------------------------------------------------------------------
__global__ __launch_bounds__(256) void gemm2_kernel(
    const float* __restrict__ H, const float* __restrict__ W2,
    const float* __restrict__ b2, float* __restrict__ X0) {
  __shared__ float Ws[NHID * NCLS];
  __shared__ float bs[NCLS];
  const int tid = threadIdx.x;
  for (int i = tid; i < NHID * NCLS; i += 256) Ws[i] = W2[i];
  if (tid < NCLS) bs[tid] = b2[tid];
  __syncthreads();
  const int node = blockIdx.x * 256 + tid;
  if (node >= NN) return;
  float acc[NCLS];
#pragma unroll
  for (int j = 0; j < NCLS; ++j) acc[j] = bs[j];
  const float4* h4 = (const float4*)(H + (long)node * NHID);
#pragma unroll
  for (int kq = 0; kq < 16; ++kq) {
    float4 h = h4[kq];
    float hv[4] = {h.x, h.y, h.z, h.w};
#pragma unroll
    for (int u = 0; u < 4; ++u) {
      const int k = kq * 4 + u;
#pragma unroll
      for (int j = 0; j < NCLS; ++j)
        acc[j] = fmaf(hv[u], Ws[k * NCLS + j], acc[j]);
    }
  }
  float* o = X0 + (long)node * NCLS;
#pragma unroll
  for (int q = 0; q < 10; ++q) {
    float4 v = make_float4(acc[q * 4], acc[q * 4 + 1], acc[q * 4 + 2], acc[q * 4 + 3]);
    *(float4*)(o + q * 4) = v;
  }
}

// ---------------------------------------------------------------------------
// CSR build: histogram -> scan -> scatter (every call; ws is re-poisoned)
// ---------------------------------------------------------------------------
__global__ __launch_bounds__(256) void hist_kernel(const int* __restrict__ row,
                                                   int* __restrict__ deg) {
  int e = blockIdx.x * 256 + threadIdx.x;
  if (e < NE) atomicAdd(&deg[row[e]], 1);
}

__global__ __launch_bounds__(1024) void scan_kernel(const int* __restrict__ deg,
                                                    int* __restrict__ rp) {
  __shared__ int sm[1024];
  const int t = threadIdx.x;
  const int CH = (NN + 1023) / 1024;  // 98
  const int i0 = t * CH;
  const int i1 = (i0 + CH < NN) ? (i0 + CH) : NN;
  int s = 0;
  for (int i = i0; i < i1; ++i) s += deg[i];
  sm[t] = s;
  __syncthreads();
  for (int off = 1; off < 1024; off <<= 1) {
    int v = (t >= off) ? sm[t - off] : 0;
    __syncthreads();
    sm[t] += v;
    __syncthreads();
  }
  int run = sm[t] - s;  // exclusive prefix
  for (int i = i0; i < i1; ++i) {
    rp[i] = run;
    run += deg[i];
  }
  if (t == 1023) rp[NN] = sm[1023];
}

__global__ __launch_bounds__(256) void scatter_kernel(
    const int* __restrict__ row, const int* __restrict__ col,
    const float* __restrict__ ev, const int* __restrict__ rp,
    int* __restrict__ cur, int2* __restrict__ edges) {
  int e = blockIdx.x * 256 + threadIdx.x;
  if (e >= NE) return;
  int r = row[e];
  int pos = rp[r] + atomicAdd(&cur[r], 1);
  edges[pos] = make_int2(col[e], __float_as_int(ev[e]));
}

// ---------------------------------------------------------------------------
// Propagation: x_out = 0.9 * (A x_in) + 0.1 * h.  10 threads per node, each
// owns 4 classes (float4). CSR gather — zero atomics; writes coalesced.
// ---------------------------------------------------------------------------
__global__ __launch_bounds__(256) void prop_kernel(
    const float4* __restrict__ xin, float4* __restrict__ xout,
    const float4* __restrict__ h, const int2* __restrict__ edges,
    const int* __restrict__ rp) {
  const int t = blockIdx.x * 256 + threadIdx.x;
  const int node = t / 10;
  if (node >= NN) return;
  const int g = t - node * 10;
  const int e0 = rp[node], e1 = rp[node + 1];
  float4 acc = make_float4(0.f, 0.f, 0.f, 0.f);
  for (int e = e0; e < e1; ++e) {
    int2 ed = edges[e];
    float v = __int_as_float(ed.y);
    float4 x = xin[(long)ed.x * 10 + g];
    acc.x = fmaf(v, x.x, acc.x);
    acc.y = fmaf(v, x.y, acc.y);
    acc.z = fmaf(v, x.z, acc.z);
    acc.w = fmaf(v, x.w, acc.w);
  }
  float4 hh = h[(long)node * 10 + g];
  float4 o;
  o.x = fmaf(0.9f, acc.x, 0.1f * hh.x);
  o.y = fmaf(0.9f, acc.y, 0.1f * hh.y);
  o.z = fmaf(0.9f, acc.z, 0.1f * hh.z);
  o.w = fmaf(0.9f, acc.w, 0.1f * hh.w);
  xout[(long)node * 10 + g] = o;
}

// ---------------------------------------------------------------------------
// log_softmax over 40 classes, one thread per node
// ---------------------------------------------------------------------------
__global__ __launch_bounds__(256) void logsm_kernel(const float* __restrict__ X,
                                                    float* __restrict__ out) {
  const int node = blockIdx.x * 256 + threadIdx.x;
  if (node >= NN) return;
  const float4* x4 = (const float4*)(X + (long)node * NCLS);
  float v[NCLS];
#pragma unroll
  for (int q = 0; q < 10; ++q) {
    float4 a = x4[q];
    v[q * 4] = a.x; v[q * 4 + 1] = a.y; v[q * 4 + 2] = a.z; v[q * 4 + 3] = a.w;
  }
  float m = v[0];
#pragma unroll
  for (int j = 1; j < NCLS; ++j) m = fmaxf(m, v[j]);
  float s = 0.f;
#pragma unroll
  for (int j = 0; j < NCLS; ++j) s += expf(v[j] - m);
  const float l = m + logf(s);
  float4* o4 = (float4*)(out + (long)node * NCLS);
#pragma unroll
  for (int q = 0; q < 10; ++q) {
    float4 a = make_float4(v[q * 4] - l, v[q * 4 + 1] - l, v[q * 4 + 2] - l,
                           v[q * 4 + 3] - l);
    o4[q] = a;
  }
}

// ---------------------------------------------------------------------------
// Launch
// ---------------------------------------------------------------------------
extern "C" void kernel_launch(void* const* d_in, const int* in_sizes, int n_in,
                              void* d_out, int out_size, void* d_ws,
                              size_t ws_size, hipStream_t stream) {
  const float* F = (const float*)d_in[0];
  const int* EI = (const int*)d_in[1];
  const float* EV = (const float*)d_in[2];
  const float* W1 = (const float*)d_in[3];
  const float* b1 = (const float*)d_in[4];
  const float* W2 = (const float*)d_in[5];
  const float* b2 = (const float*)d_in[6];
  float* out = (float*)d_out;
  char* ws = (char*)d_ws;

  // ws layout (bytes), all offsets 256-aligned:
  //   X0 : [0, 16,000,000)            N*40 f32 (also the residual h)
  //   XA : [16,000,000, 32,000,000)
  //   XB : [32,000,000, 48,000,000)
  //   H  : [48,000,000, 73,600,000)   N*64 f32; REUSED as int2 edges (E*8 == N*64*4)
  //   RP : [73,600,000, +400,004)     row_ptr (N+1)
  //   CUR: [74,000,128, +400,000)     degree/cursor
  float* X0 = (float*)(ws + 0);
  float* XA = (float*)(ws + 16000000);
  float* XB = (float*)(ws + 32000000);
  float* H = (float*)(ws + 48000000);
  int2* EDG = (int2*)(ws + 48000000);  // alias of H; H is dead after gemm2
  int* RP = (int*)(ws + 73600000);
  int* CUR = (int*)(ws + 74000128);

  const int* ROW = EI;       // edge_index[0]
  const int* COL = EI + NE;  // edge_index[1]

  gemm1_kernel<<<(NN + 63) / 64, 256, 0, stream>>>(F, W1, b1, H);
  gemm2_kernel<<<(NN + 255) / 256, 256, 0, stream>>>(H, W2, b2, X0);

  hipMemsetAsync(CUR, 0, NN * sizeof(int), stream);
  hist_kernel<<<(NE + 255) / 256, 256, 0, stream>>>(ROW, CUR);
  scan_kernel<<<1, 1024, 0, stream>>>(CUR, RP);
  hipMemsetAsync(CUR, 0, NN * sizeof(int), stream);
  scatter_kernel<<<(NE + 255) / 256, 256, 0, stream>>>(ROW, COL, EV, RP, CUR, EDG);

  const int tgrid = (NN * 10 + 255) / 256;
  const float* cur_in = X0;
  float* bufs[2] = {XA, XB};
  for (int it = 0; it < 10; ++it) {
    float* o = bufs[it & 1];
    prop_kernel<<<tgrid, 256, 0, stream>>>((const float4*)cur_in, (float4*)o,
                                           (const float4*)X0, EDG, RP);
    cur_in = o;
  }
  logsm_kernel<<<(NN + 255) / 256, 256, 0, stream>>>(cur_in, out);
}